// Round 4
// baseline (40.300 us; speedup 1.0000x reference)
//
#include <hip/hip_runtime.h>
#include <math.h>

#define N_LABELS 50
#define NCLS 80
#define LOG2C 0.693147180559945f

// grid geometry: ceil(3*19*19/256)=5, ceil(3*38*38/256)=17, ceil(3*76*76/256)=68 per batch
#define NB_L0 80      // 5*16
#define NB_L1 272     // 17*16
#define NB_L2 1088    // 68*16
#define N_MAIN 1440
#define N_CORR 12
#define N_BLOCKS 1452
#define N_PART (N_BLOCKS * 4)

__device__ __constant__ float d_anchors[9][2] = {
    {10.f,13.f},{16.f,30.f},{33.f,23.f},{30.f,61.f},{62.f,45.f},
    {59.f,119.f},{116.f,90.f},{156.f,198.f},{373.f,326.f}
};
// anchors/stride per layer: layer0=19x19(s32,g2), layer1=38x38(s16,g1), layer2=76x76(s8,g0)
__device__ __constant__ float d_anch_scaled[3][3][2] = {
    {{3.625f, 2.8125f}, {4.875f, 6.1875f}, {11.65625f, 10.1875f}},
    {{1.875f, 3.8125f}, {3.875f, 2.8125f}, {3.6875f, 7.4375f}},
    {{1.25f, 1.625f},   {2.0f, 3.75f},     {4.125f, 2.875f}}
};

// label box table: [layer][b][label][8] = {x0,y0,x1,y1, ta*0.7/1.7, pad,pad,pad}
__device__ float g_ltab[3 * 16 * N_LABELS * 8];
__device__ float g_part[N_PART];

__device__ __forceinline__ float softplus_f(float x) {      // == bce(x, 0)
    return fmaxf(x, 0.f) + __logf(1.f + __expf(-fabsf(x)));
}
__device__ __forceinline__ float bce_f(float x, float z) {
    return fmaxf(x, 0.f) - x * z + __logf(1.f + __expf(-fabsf(x)));
}
__device__ __forceinline__ float sigmoid_f(float x) {
    return __builtin_amdgcn_rcpf(1.f + __expf(-x));
}

// ---------------- prep: build per-layer label box tables ----------------
__global__ __launch_bounds__(256) void prep_kernel(const float* __restrict__ tgt) {
    int r = blockIdx.x * 256 + threadIdx.x;          // 3*16*50 = 2400 records
    if (r < 3 * 16 * N_LABELS) {
        int layer = r / (16 * N_LABELS);
        int rem = r - layer * 16 * N_LABELS;
        int b = rem / N_LABELS, l = rem - b * N_LABELS;
        float wdim = (layer == 0) ? 19.f : (layer == 1) ? 38.f : 76.f;
        const float* lp = tgt + ((size_t)b * N_LABELS + l) * 5;
        float tx = lp[1] * wdim, ty = lp[2] * wdim;
        float tw = lp[3] * wdim, th = lp[4] * wdim;
        float* o = g_ltab + (size_t)r * 8;
        o[0] = tx - 0.5f * tw;
        o[1] = ty - 0.5f * th;
        o[2] = tx + 0.5f * tw;
        o[3] = ty + 0.5f * th;
        o[4] = tw * th * (0.7f / 1.7f);
    }
}

// ---------------- main uniform pass: one cell per thread, no LDS, no sync ----------------
template<int H, int W, int GROUP, int LAYER>
__device__ __forceinline__ void main_part(const float* __restrict__ out,
        int b, int chunk)
{
    constexpr int HW = H * W;
    constexpr int NC = 3 * HW;
    int tid = threadIdx.x;
    int cell = chunk * 256 + tid;
    bool valid = (cell < NC);
    int cc = valid ? cell : 0;
    int a = cc / HW, rem = cc - a * HW;
    int hh = rem / W, ww = rem - hh * W;
    const float* base = out + ((size_t)b * 255 + (size_t)a * 85) * HW + rem;
    float c0 = base[0];
    float c1 = base[HW];
    float c2 = base[2 * (size_t)HW];
    float c3 = base[3 * (size_t)HW];
    float c4 = base[4 * (size_t)HW];

    float aw = d_anch_scaled[LAYER][a][0];
    float ah = d_anch_scaled[LAYER][a][1];
    float pw = __expf(c2) * aw, ph = __expf(c3) * ah;
    float px = sigmoid_f(c0) + (float)ww;
    float py = sigmoid_f(c1) + (float)hh;
    float x0 = px - 0.5f * pw, x1 = px + 0.5f * pw;
    float y0 = py - 0.5f * ph, y1 = py + 0.5f * ph;
    float p07 = pw * ph * (0.7f / 1.7f);
    float whb = 0.5f * (c2 * c2 + c3 * c3);          // unmasked wh (warm-up prior) term

    // block-uniform label table -> scalar loads (SMEM pipe), no LDS
    const float* lb = g_ltab + (size_t)((LAYER * 16 + b) * N_LABELS) * 8;
    bool ign = false;
    #pragma unroll 5
    for (int l = 0; l < N_LABELS; ++l) {
        float bx0 = lb[l * 8 + 0];
        float by0 = lb[l * 8 + 1];
        float bx1 = lb[l * 8 + 2];
        float by1 = lb[l * 8 + 3];
        float ba  = lb[l * 8 + 4];
        float w_ = fminf(x1, bx1) - fmaxf(x0, bx0);
        float h_ = fminf(y1, by1) - fmaxf(y0, by0);
        // iou > 0.7  <=>  inter > 0.7/1.7 * (parea + tarea)   (no division)
        bool hit = (fminf(w_, h_) > 0.f) && (w_ * h_ > ba + p07);
        ign = ign || hit;
    }

    float lsum = valid ? ((ign ? LOG2C : softplus_f(c4)) + 80.f * LOG2C + whb) : 0.f;

    #pragma unroll
    for (int off = 32; off > 0; off >>= 1)
        lsum += __shfl_down(lsum, off);
    if ((tid & 63) == 0)
        g_part[blockIdx.x * 4 + (tid >> 6)] = lsum;
}

// ---------------- correction pass: matched-label deltas (rare path) ----------------
template<int H, int W, int STRIDE, int GROUP>
__device__ __forceinline__ void corr_part(const float* __restrict__ out,
        const float* __restrict__ tgt, int bbase,
        float4 (*sbox)[N_LABELS], float (*slin_f)[64])
{
    constexpr int HW = H * W;
    int tid = threadIdx.x, wid = tid >> 6, lane = tid & 63;
    int b = bbase + wid;
    int* slin = (int*)slin_f;

    float tx=0, ty=0, tw=0, th=0, lw=0, lh=0, sc=0;
    int lin = -1, cls = 0;
    if (lane < N_LABELS) {
        const float* lp = tgt + ((size_t)b * N_LABELS + lane) * 5;
        cls = (int)lp[0];
        tx = lp[1] * (float)W; ty = lp[2] * (float)H;
        tw = lp[3] * (float)W; th = lp[4] * (float)H;
        float ta = tw * th;
        sbox[wid][lane] = make_float4(tx - 0.5f*tw, ty - 0.5f*th, tx + 0.5f*tw, ty + 0.5f*th);
        float best_iou = -1.f; int best = 0;
        #pragma unroll
        for (int kk = 0; kk < 9; ++kk) {
            float rw = d_anchors[kk][0] * (1.f / (float)STRIDE);
            float rh = d_anchors[kk][1] * (1.f / (float)STRIDE);
            float mx = fminf(tw, rw), my = fminf(th, rh);
            float inter = (mx > 0.f && my > 0.f) ? mx * my : 0.f;
            float iou = inter / (ta + rw * rh - inter);
            if (iou > best_iou) { best_iou = iou; best = kk; }
        }
        int bn = best - (best / 3) * 3;
        float aw = d_anchors[GROUP*3 + bn][0] * (1.f / (float)STRIDE);
        float ah = d_anchors[GROUP*3 + bn][1] * (1.f / (float)STRIDE);
        lw = __logf(tw / aw + 1e-16f);
        lh = __logf(th / ah + 1e-16f);
        sc = sqrtf(2.f - tw * th * (1.f / (float)HW));
        if (best / 3 == GROUP) {
            int ti = (int)tx, tj = (int)ty;
            lin = (bn * H + tj) * W + ti;
        }
    }
    slin[wid * 64 + lane] = lin;
    __syncthreads();

    bool active = (lin >= 0);
    if (active) {                       // last-write-wins on duplicate cells
        for (int l2 = lane + 1; l2 < N_LABELS; ++l2)
            if (slin[wid * 64 + l2] == lin) active = false;
    }

    float lsum = 0.f;
    if (active) {
        int a = lin / HW, rem = lin - a * HW;
        int hh = rem / W, ww = rem - hh * W;
        const float* base = out + ((size_t)b * 255 + (size_t)a * 85) * HW + rem;
        float c0 = base[0];
        float c1 = base[HW];
        float c2 = base[2 * (size_t)HW];
        float c3 = base[3 * (size_t)HW];
        float c4 = base[4 * (size_t)HW];
        float aw = d_anchors[GROUP*3 + a][0] * (1.f / (float)STRIDE);
        float ah = d_anchors[GROUP*3 + a][1] * (1.f / (float)STRIDE);
        float pw = __expf(c2) * aw, ph = __expf(c3) * ah;
        float px = sigmoid_f(c0) + (float)ww;
        float py = sigmoid_f(c1) + (float)hh;
        float X0 = px - 0.5f*pw, X1 = px + 0.5f*pw;
        float Y0 = py - 0.5f*ph, Y1 = py + 0.5f*ph;
        float p07 = pw * ph * (0.7f / 1.7f);
        bool ign = false;
        for (int l = 0; l < N_LABELS; ++l) {
            float4 tb = sbox[wid][l];
            float ta07 = (tb.z - tb.x) * (tb.w - tb.y) * (0.7f / 1.7f);
            float w_ = fminf(X1, tb.z) - fmaxf(X0, tb.x);
            float h_ = fminf(Y1, tb.w) - fmaxf(Y0, tb.y);
            ign = ign || ((fminf(w_, h_) > 0.f) && (w_ * h_ > ta07 + p07));
        }
        float baseobj = ign ? LOG2C : softplus_f(c4);   // what main_part added for obj
        lsum += bce_f(c4, 1.f) - baseobj;
        float s2 = sc * sc;
        float txf = tx - (float)(int)tx, tyf = ty - (float)(int)ty;
        lsum += (bce_f(c0, txf) + bce_f(c1, tyf)) * s2;
        float dw = c2 - lw, dh = c3 - lh;
        lsum += 0.5f * (dw*dw + dh*dh) * s2;
        float csum = 0.f;
        for (int c = 0; c < NCLS; ++c) {
            float lg = base[(size_t)(5 + c) * HW];
            csum += bce_f(lg, (c == cls) ? 1.f : 0.f);
        }
        lsum += csum - 80.f * LOG2C;
    }

    #pragma unroll
    for (int off = 32; off > 0; off >>= 1)
        lsum += __shfl_down(lsum, off);
    if (lane == 0)
        g_part[blockIdx.x * 4 + wid] = lsum;
}

// Grid: L0: 80 | L1: 272 | L2: 1088 | corr: 12  => 1452
__global__ __launch_bounds__(256) void yolo_main(
        const float* __restrict__ o0, const float* __restrict__ o1,
        const float* __restrict__ o2, const float* __restrict__ tgt)
{
    int bid = blockIdx.x;
    if (bid < NB_L0) {
        main_part<19,19,2,0>(o0, bid / 5, bid % 5);
    } else if (bid < NB_L0 + NB_L1) {
        int id = bid - NB_L0;
        main_part<38,38,1,1>(o1, id / 17, id % 17);
    } else if (bid < N_MAIN) {
        int id = bid - (NB_L0 + NB_L1);
        main_part<76,76,0,2>(o2, id / 68, id % 68);
    } else {
        __shared__ float4 sbox[4][N_LABELS];
        __shared__ float  slin_f[4][64];
        int cb = bid - N_MAIN;              // 0..11
        int layer = cb >> 2, bbase = (cb & 3) * 4;
        if (layer == 0)      corr_part<19,19,32,2>(o0, tgt, bbase, sbox, slin_f);
        else if (layer == 1) corr_part<38,38,16,1>(o1, tgt, bbase, sbox, slin_f);
        else                 corr_part<76,76,8,0>(o2, tgt, bbase, sbox, slin_f);
    }
}

__global__ __launch_bounds__(256) void reduce_partials(float* __restrict__ loss)
{
    int tid = threadIdx.x;
    float v = 0.f;
    for (int i = tid; i < N_PART; i += 256)
        v += g_part[i];
    __shared__ float wsums[4];
    #pragma unroll
    for (int off = 32; off > 0; off >>= 1)
        v += __shfl_down(v, off);
    if ((tid & 63) == 0) wsums[tid >> 6] = v;
    __syncthreads();
    if (tid == 0) *loss = wsums[0] + wsums[1] + wsums[2] + wsums[3];
}

extern "C" void kernel_launch(void* const* d_in, const int* in_sizes, int n_in,
                              void* d_out, int out_size, void* d_ws, size_t ws_size,
                              hipStream_t stream) {
    const float* o0  = (const float*)d_in[0];
    const float* o1  = (const float*)d_in[1];
    const float* o2  = (const float*)d_in[2];
    const float* tgt = (const float*)d_in[3];
    float* loss = (float*)d_out;
    prep_kernel<<<10, 256, 0, stream>>>(tgt);
    yolo_main<<<N_BLOCKS, 256, 0, stream>>>(o0, o1, o2, tgt);
    reduce_partials<<<1, 256, 0, stream>>>(loss);
}

// Round 5
// 33.305 us; speedup vs baseline: 1.2100x; 1.2100x over previous
//
#include <hip/hip_runtime.h>
#include <math.h>

#define N_LABELS 50
#define NCLS 80
#define LOG2C 0.693147180559945f
#define N_MAIN_BLOCKS 736
#define N_CORR_BLOCKS 12
#define N_BLOCKS (N_MAIN_BLOCKS + N_CORR_BLOCKS)

__device__ __constant__ float d_anchors[9][2] = {
    {10.f,13.f},{16.f,30.f},{33.f,23.f},{30.f,61.f},{62.f,45.f},
    {59.f,119.f},{116.f,90.f},{156.f,198.f},{373.f,326.f}
};

__device__ float g_part[N_BLOCKS];
__device__ int   g_count;        // zero-init at module load; winner resets to 0 each call

__device__ __forceinline__ float softplus_f(float x) {      // == bce(x, 0)
    return fmaxf(x, 0.f) + __logf(1.f + __expf(-fabsf(x)));
}
__device__ __forceinline__ float bce_f(float x, float z) {
    return fmaxf(x, 0.f) - x * z + __logf(1.f + __expf(-fabsf(x)));
}
__device__ __forceinline__ float sigmoid_f(float x) {
    return __builtin_amdgcn_rcpf(1.f + __expf(-x));
}

// ---------------- main uniform pass: every cell, no divergence ----------------
template<int H, int W, int GROUP>
__device__ __forceinline__ float main_part(const float* __restrict__ out,
        const float* __restrict__ tgt, int b, int chunk, float4* sbox)
{
    constexpr int HW = H * W;
    constexpr int NC = 3 * HW;
    int tid = threadIdx.x;

    if (tid < N_LABELS) {
        const float* lp = tgt + ((size_t)b * N_LABELS + tid) * 5;
        float tx = lp[1] * (float)W, ty = lp[2] * (float)H;
        float tw = lp[3] * (float)W, th = lp[4] * (float)H;
        sbox[tid] = make_float4(tx - 0.5f*tw, ty - 0.5f*th, tx + 0.5f*tw, ty + 0.5f*th);
    }
    __syncthreads();

    const float* ob = out + (size_t)b * 255 * HW;
    int c0i = chunk * 512 + tid;
    float x0[2], x1[2], y0[2], y1[2], p07[2], c4v[2], whb[2];
    bool valid[2], ign[2];

    #pragma unroll
    for (int k = 0; k < 2; ++k) {
        int cell = c0i + k * 256;
        valid[k] = (cell < NC);
        int cc = valid[k] ? cell : 0;
        int a = cc / HW, rem = cc - a * HW;
        int hh = rem / W, ww = rem - hh * W;
        const float* base = ob + (size_t)a * 85 * HW + rem;
        float c0 = base[0];
        float c1 = base[HW];
        float c2 = base[2 * (size_t)HW];
        float c3 = base[3 * (size_t)HW];
        c4v[k] = base[4 * (size_t)HW];
        float aw = d_anchors[GROUP*3 + a][0] * (1.f / (float)(608 / W));
        float ah = d_anchors[GROUP*3 + a][1] * (1.f / (float)(608 / W));
        float pw = __expf(c2) * aw, ph = __expf(c3) * ah;
        float px = sigmoid_f(c0) + (float)ww;
        float py = sigmoid_f(c1) + (float)hh;
        x0[k] = px - 0.5f*pw; x1[k] = px + 0.5f*pw;
        y0[k] = py - 0.5f*ph; y1[k] = py + 0.5f*ph;
        p07[k] = pw * ph * (0.7f / 1.7f);
        whb[k] = 0.5f * (c2*c2 + c3*c3);      // unmasked wh (warm-up prior) term
        ign[k] = false;
    }

    #pragma unroll 5
    for (int l = 0; l < N_LABELS; ++l) {
        float4 tb = sbox[l];
        float ta07 = (tb.z - tb.x) * (tb.w - tb.y) * (0.7f / 1.7f);
        #pragma unroll
        for (int k = 0; k < 2; ++k) {
            float w_ = fminf(x1[k], tb.z) - fmaxf(x0[k], tb.x);
            float h_ = fminf(y1[k], tb.w) - fmaxf(y0[k], tb.y);
            // iou > 0.7  <=>  inter > 0.7/1.7 * (parea + tarea)   (no division)
            bool hit = (fminf(w_, h_) > 0.f) && (w_ * h_ > ta07 + p07[k]);
            ign[k] = ign[k] || hit;
        }
    }

    float lsum = 0.f;
    #pragma unroll
    for (int k = 0; k < 2; ++k)
        if (valid[k])
            lsum += (ign[k] ? LOG2C : softplus_f(c4v[k])) + 80.f * LOG2C + whb[k];
    return lsum;
}

// ---------------- correction pass: matched-label deltas (rare path) ----------------
template<int H, int W, int STRIDE, int GROUP>
__device__ __forceinline__ float corr_part(const float* __restrict__ out,
        const float* __restrict__ tgt, int bbase,
        float4 (*sbox)[N_LABELS], float (*slin_f)[64])
{
    constexpr int HW = H * W;
    int tid = threadIdx.x, wid = tid >> 6, lane = tid & 63;
    int b = bbase + wid;
    int* slin = (int*)slin_f;

    float tx=0, ty=0, tw=0, th=0, lw=0, lh=0, sc=0;
    int lin = -1, cls = 0;
    if (lane < N_LABELS) {
        const float* lp = tgt + ((size_t)b * N_LABELS + lane) * 5;
        cls = (int)lp[0];
        tx = lp[1] * (float)W; ty = lp[2] * (float)H;
        tw = lp[3] * (float)W; th = lp[4] * (float)H;
        float ta = tw * th;
        sbox[wid][lane] = make_float4(tx - 0.5f*tw, ty - 0.5f*th, tx + 0.5f*tw, ty + 0.5f*th);
        float best_iou = -1.f; int best = 0;
        #pragma unroll
        for (int kk = 0; kk < 9; ++kk) {
            float rw = d_anchors[kk][0] * (1.f / (float)STRIDE);
            float rh = d_anchors[kk][1] * (1.f / (float)STRIDE);
            float mx = fminf(tw, rw), my = fminf(th, rh);
            float inter = (mx > 0.f && my > 0.f) ? mx * my : 0.f;
            float iou = inter / (ta + rw * rh - inter);
            if (iou > best_iou) { best_iou = iou; best = kk; }
        }
        int bn = best - (best / 3) * 3;
        float aw = d_anchors[GROUP*3 + bn][0] * (1.f / (float)STRIDE);
        float ah = d_anchors[GROUP*3 + bn][1] * (1.f / (float)STRIDE);
        lw = __logf(tw / aw + 1e-16f);
        lh = __logf(th / ah + 1e-16f);
        sc = sqrtf(2.f - tw * th * (1.f / (float)HW));
        if (best / 3 == GROUP) {
            int ti = (int)tx, tj = (int)ty;
            lin = (bn * H + tj) * W + ti;
        }
    }
    slin[wid * 64 + lane] = lin;
    __syncthreads();

    bool active = (lin >= 0);
    if (active) {                       // last-write-wins on duplicate cells
        for (int l2 = lane + 1; l2 < N_LABELS; ++l2)
            if (slin[wid * 64 + l2] == lin) active = false;
    }

    float lsum = 0.f;
    if (active) {
        int a = lin / HW, rem = lin - a * HW;
        int hh = rem / W, ww = rem - hh * W;
        const float* base = out + ((size_t)b * 255 + (size_t)a * 85) * HW + rem;
        float c0 = base[0];
        float c1 = base[HW];
        float c2 = base[2 * (size_t)HW];
        float c3 = base[3 * (size_t)HW];
        float c4 = base[4 * (size_t)HW];
        float aw = d_anchors[GROUP*3 + a][0] * (1.f / (float)STRIDE);
        float ah = d_anchors[GROUP*3 + a][1] * (1.f / (float)STRIDE);
        float pw = __expf(c2) * aw, ph = __expf(c3) * ah;
        float px = sigmoid_f(c0) + (float)ww;
        float py = sigmoid_f(c1) + (float)hh;
        float X0 = px - 0.5f*pw, X1 = px + 0.5f*pw;
        float Y0 = py - 0.5f*ph, Y1 = py + 0.5f*ph;
        float p07 = pw * ph * (0.7f / 1.7f);
        bool ign = false;
        for (int l = 0; l < N_LABELS; ++l) {
            float4 tb = sbox[wid][l];
            float ta07 = (tb.z - tb.x) * (tb.w - tb.y) * (0.7f / 1.7f);
            float w_ = fminf(X1, tb.z) - fmaxf(X0, tb.x);
            float h_ = fminf(Y1, tb.w) - fmaxf(Y0, tb.y);
            ign = ign || ((fminf(w_, h_) > 0.f) && (w_ * h_ > ta07 + p07));
        }
        float baseobj = ign ? LOG2C : softplus_f(c4);   // what main_part added for obj
        lsum += bce_f(c4, 1.f) - baseobj;
        float s2 = sc * sc;
        float txf = tx - (float)(int)tx, tyf = ty - (float)(int)ty;
        lsum += (bce_f(c0, txf) + bce_f(c1, tyf)) * s2;
        float dw = c2 - lw, dh = c3 - lh;
        lsum += 0.5f * (dw*dw + dh*dh) * s2;
        float csum = 0.f;
        for (int c = 0; c < NCLS; ++c) {
            float lg = base[(size_t)(5 + c) * HW];
            csum += bce_f(lg, (c == cls) ? 1.f : 0.f);
        }
        lsum += csum - 80.f * LOG2C;
    }
    return lsum;
}

// Grid: L0: 3 chunks x16 = 48 | L1: 9x16 = 144 | L2: 34x16 = 544 | corr: 12  => 748
// Single launch: last block (device-scope atomic counter) reduces all partials.
__global__ __launch_bounds__(256) void yolo_main(
        const float* __restrict__ o0, const float* __restrict__ o1,
        const float* __restrict__ o2, const float* __restrict__ tgt,
        float* __restrict__ loss)
{
    __shared__ float4 sbox[4][N_LABELS];
    __shared__ float  slin_f[4][64];
    __shared__ float  wsums[4];
    __shared__ int    sflag;
    int bid = blockIdx.x, tid = threadIdx.x;

    float lsum;
    if (bid < 48) {
        lsum = main_part<19,19,2>(o0, tgt, bid / 3, bid % 3, &sbox[0][0]);
    } else if (bid < 192) {
        int id = bid - 48;
        lsum = main_part<38,38,1>(o1, tgt, id / 9, id % 9, &sbox[0][0]);
    } else if (bid < N_MAIN_BLOCKS) {
        int id = bid - 192;
        lsum = main_part<76,76,0>(o2, tgt, id / 34, id % 34, &sbox[0][0]);
    } else {
        int cb = bid - N_MAIN_BLOCKS;       // 0..11
        int layer = cb >> 2, bbase = (cb & 3) * 4;
        if (layer == 0)      lsum = corr_part<19,19,32,2>(o0, tgt, bbase, sbox, slin_f);
        else if (layer == 1) lsum = corr_part<38,38,16,1>(o1, tgt, bbase, sbox, slin_f);
        else                 lsum = corr_part<76,76,8,0>(o2, tgt, bbase, sbox, slin_f);
    }

    // block reduce -> one partial per block
    #pragma unroll
    for (int off = 32; off > 0; off >>= 1)
        lsum += __shfl_down(lsum, off);
    if ((tid & 63) == 0) wsums[tid >> 6] = lsum;
    __syncthreads();

    if (tid == 0) {
        g_part[bid] = wsums[0] + wsums[1] + wsums[2] + wsums[3];
        __threadfence();                            // release our partial
        int old = atomicAdd(&g_count, 1);           // device-scope
        sflag = (old == N_BLOCKS - 1) ? 1 : 0;
    }
    __syncthreads();

    if (sflag) {                                    // last block: deterministic final sum
        __threadfence();                            // acquire all partials
        float v = 0.f;
        for (int i = tid; i < N_BLOCKS; i += 256)
            v += g_part[i];
        #pragma unroll
        for (int off = 32; off > 0; off >>= 1)
            v += __shfl_down(v, off);
        if ((tid & 63) == 0) wsums[tid >> 6] = v;
        __syncthreads();
        if (tid == 0) {
            *loss = wsums[0] + wsums[1] + wsums[2] + wsums[3];
            g_count = 0;                            // restore invariant for next replay
        }
    }
}

extern "C" void kernel_launch(void* const* d_in, const int* in_sizes, int n_in,
                              void* d_out, int out_size, void* d_ws, size_t ws_size,
                              hipStream_t stream) {
    const float* o0  = (const float*)d_in[0];
    const float* o1  = (const float*)d_in[1];
    const float* o2  = (const float*)d_in[2];
    const float* tgt = (const float*)d_in[3];
    float* loss = (float*)d_out;
    yolo_main<<<N_BLOCKS, 256, 0, stream>>>(o0, o1, o2, tgt, loss);
}

// Round 6
// 27.765 us; speedup vs baseline: 1.4515x; 1.1995x over previous
//
#include <hip/hip_runtime.h>
#include <math.h>

#define N_LABELS 50
#define NCLS 80
#define LOG2C 0.693147180559945f
#define N_CORR_BLOCKS 12
#define N_MAIN_BLOCKS 736
#define N_BLOCKS (N_MAIN_BLOCKS + N_CORR_BLOCKS)

__device__ __constant__ float d_anchors[9][2] = {
    {10.f,13.f},{16.f,30.f},{33.f,23.f},{30.f,61.f},{62.f,45.f},
    {59.f,119.f},{116.f,90.f},{156.f,198.f},{373.f,326.f}
};

__device__ float g_slots[64];    // zero-init at load; winner resets each call
__device__ int   g_count;

__device__ __forceinline__ float softplus_f(float x) {      // == bce(x, 0)
    return fmaxf(x, 0.f) + __logf(1.f + __expf(-fabsf(x)));
}
__device__ __forceinline__ float bce_f(float x, float z) {
    return fmaxf(x, 0.f) - x * z + __logf(1.f + __expf(-fabsf(x)));
}
__device__ __forceinline__ float sigmoid_f(float x) {
    return __builtin_amdgcn_rcpf(1.f + __expf(-x));
}

// ---------------- main uniform pass: every cell, no divergence ----------------
template<int H, int W, int GROUP>
__device__ __forceinline__ float main_part(const float* __restrict__ out,
        const float* __restrict__ tgt, int b, int chunk,
        float4* sbox, float* sta)
{
    constexpr int HW = H * W;
    constexpr int NC = 3 * HW;
    constexpr int STRIDE = 608 / W;
    int tid = threadIdx.x;

    if (tid < N_LABELS) {
        const float* lp = tgt + ((size_t)b * N_LABELS + tid) * 5;
        float tx = lp[1] * (float)W, ty = lp[2] * (float)H;
        float tw = lp[3] * (float)W, th = lp[4] * (float)H;
        sbox[tid] = make_float4(tx - 0.5f*tw, ty - 0.5f*th, tx + 0.5f*tw, ty + 0.5f*th);
        sta[tid] = tw * th * (0.7f / 1.7f);
    }
    __syncthreads();

    const float* ob = out + (size_t)b * 255 * HW;
    int c0i = chunk * 512 + tid;
    float x0[2], x1[2], y0[2], y1[2], p07[2], c4v[2], whb[2];
    bool valid[2], ign[2];

    #pragma unroll
    for (int k = 0; k < 2; ++k) {
        int cell = c0i + k * 256;
        valid[k] = (cell < NC);
        int cc = valid[k] ? cell : 0;
        int a = cc / HW, rem = cc - a * HW;
        int hh = rem / W, ww = rem - hh * W;
        const float* base = ob + (size_t)a * 85 * HW + rem;
        float c0 = base[0];
        float c1 = base[HW];
        float c2 = base[2 * (size_t)HW];
        float c3 = base[3 * (size_t)HW];
        c4v[k] = base[4 * (size_t)HW];
        float aw = d_anchors[GROUP*3 + a][0] * (1.f / (float)STRIDE);
        float ah = d_anchors[GROUP*3 + a][1] * (1.f / (float)STRIDE);
        float pw = __expf(c2) * aw, ph = __expf(c3) * ah;
        float px = sigmoid_f(c0) + (float)ww;
        float py = sigmoid_f(c1) + (float)hh;
        x0[k] = px - 0.5f*pw; x1[k] = px + 0.5f*pw;
        y0[k] = py - 0.5f*ph; y1[k] = py + 0.5f*ph;
        p07[k] = pw * ph * (0.7f / 1.7f);
        whb[k] = 0.5f * (c2*c2 + c3*c3);      // unmasked wh (warm-up prior) term
        ign[k] = false;
    }

    #pragma unroll 5
    for (int l = 0; l < N_LABELS; ++l) {
        float4 tb = sbox[l];
        float ta07 = sta[l];
        #pragma unroll
        for (int k = 0; k < 2; ++k) {
            float w_ = fminf(x1[k], tb.z) - fmaxf(x0[k], tb.x);
            float h_ = fminf(y1[k], tb.w) - fmaxf(y0[k], tb.y);
            // iou > 0.7  <=>  inter > 0.7/1.7 * (parea + tarea)   (no division)
            bool hit = (fminf(w_, h_) > 0.f) && (w_ * h_ > ta07 + p07[k]);
            ign[k] = ign[k] || hit;
        }
    }

    float lsum = 0.f;
    #pragma unroll
    for (int k = 0; k < 2; ++k)
        if (valid[k])
            lsum += (ign[k] ? LOG2C : softplus_f(c4v[k])) + 80.f * LOG2C + whb[k];
    return lsum;
}

// ---------------- correction pass: matched-label deltas (rare path) ----------------
template<int H, int W, int STRIDE, int GROUP>
__device__ __forceinline__ float corr_part(const float* __restrict__ out,
        const float* __restrict__ tgt, int bbase,
        float4 (*sbox)[N_LABELS], int* slin)
{
    constexpr int HW = H * W;
    int tid = threadIdx.x, wid = tid >> 6, lane = tid & 63;
    int b = bbase + wid;

    float tx=0, ty=0, tw=0, th=0, lw=0, lh=0, sc=0;
    int lin = -1, cls = 0;
    if (lane < N_LABELS) {
        const float* lp = tgt + ((size_t)b * N_LABELS + lane) * 5;
        cls = (int)lp[0];
        tx = lp[1] * (float)W; ty = lp[2] * (float)H;
        tw = lp[3] * (float)W; th = lp[4] * (float)H;
        float ta = tw * th;
        sbox[wid][lane] = make_float4(tx - 0.5f*tw, ty - 0.5f*th, tx + 0.5f*tw, ty + 0.5f*th);
        float best_iou = -1.f; int best = 0;
        #pragma unroll
        for (int kk = 0; kk < 9; ++kk) {
            float rw = d_anchors[kk][0] * (1.f / (float)STRIDE);
            float rh = d_anchors[kk][1] * (1.f / (float)STRIDE);
            float mx = fminf(tw, rw), my = fminf(th, rh);
            float inter = (mx > 0.f && my > 0.f) ? mx * my : 0.f;
            float iou = inter / (ta + rw * rh - inter);
            if (iou > best_iou) { best_iou = iou; best = kk; }
        }
        int bn = best - (best / 3) * 3;
        float aw = d_anchors[GROUP*3 + bn][0] * (1.f / (float)STRIDE);
        float ah = d_anchors[GROUP*3 + bn][1] * (1.f / (float)STRIDE);
        lw = __logf(tw / aw + 1e-16f);
        lh = __logf(th / ah + 1e-16f);
        sc = sqrtf(2.f - tw * th * (1.f / (float)HW));
        if (best / 3 == GROUP) {
            int ti = (int)tx, tj = (int)ty;
            lin = (bn * H + tj) * W + ti;
        }
    }
    slin[wid * 64 + lane] = lin;
    __syncthreads();

    bool active = (lin >= 0);
    if (active) {                       // last-write-wins on duplicate cells
        for (int l2 = lane + 1; l2 < N_LABELS; ++l2)
            if (slin[wid * 64 + l2] == lin) active = false;
    }

    float lsum = 0.f;
    if (active) {
        int a = lin / HW, rem = lin - a * HW;
        int hh = rem / W, ww = rem - hh * W;
        const float* base = out + ((size_t)b * 255 + (size_t)a * 85) * HW + rem;
        float c0 = base[0];
        float c1 = base[HW];
        float c2 = base[2 * (size_t)HW];
        float c3 = base[3 * (size_t)HW];
        float c4 = base[4 * (size_t)HW];
        float aw = d_anchors[GROUP*3 + a][0] * (1.f / (float)STRIDE);
        float ah = d_anchors[GROUP*3 + a][1] * (1.f / (float)STRIDE);
        float pw = __expf(c2) * aw, ph = __expf(c3) * ah;
        float px = sigmoid_f(c0) + (float)ww;
        float py = sigmoid_f(c1) + (float)hh;
        float X0 = px - 0.5f*pw, X1 = px + 0.5f*pw;
        float Y0 = py - 0.5f*ph, Y1 = py + 0.5f*ph;
        float p07 = pw * ph * (0.7f / 1.7f);
        bool ign = false;
        for (int l = 0; l < N_LABELS; ++l) {
            float4 tb = sbox[wid][l];
            float ta07 = (tb.z - tb.x) * (tb.w - tb.y) * (0.7f / 1.7f);
            float w_ = fminf(X1, tb.z) - fmaxf(X0, tb.x);
            float h_ = fminf(Y1, tb.w) - fmaxf(Y0, tb.y);
            ign = ign || ((fminf(w_, h_) > 0.f) && (w_ * h_ > ta07 + p07));
        }
        float baseobj = ign ? LOG2C : softplus_f(c4);   // what main_part added for obj
        lsum += bce_f(c4, 1.f) - baseobj;
        float s2 = sc * sc;
        float txf = tx - (float)(int)tx, tyf = ty - (float)(int)ty;
        lsum += (bce_f(c0, txf) + bce_f(c1, tyf)) * s2;
        float dw = c2 - lw, dh = c3 - lh;
        lsum += 0.5f * (dw*dw + dh*dh) * s2;
        float csum = 0.f;
        for (int c = 0; c < NCLS; ++c) {
            float lg = base[(size_t)(5 + c) * HW];
            csum += bce_f(lg, (c == cls) ? 1.f : 0.f);
        }
        lsum += csum - 80.f * LOG2C;
    }
    return lsum;
}

// Grid: corr: 12 (FIRST, to overlap their latency-bound tail) | then mains: 736.
// Single launch; last-arriving block reduces 64 atomic slots (no threadfence/wbL2).
__global__ __launch_bounds__(256) void yolo_main(
        const float* __restrict__ o0, const float* __restrict__ o1,
        const float* __restrict__ o2, const float* __restrict__ tgt,
        float* __restrict__ loss)
{
    __shared__ float4 sbox[4][N_LABELS];
    __shared__ float  sta4[4][N_LABELS];
    __shared__ int    slin[4 * 64];
    __shared__ float  wsums[4];
    __shared__ int    sflag;
    int bid = blockIdx.x, tid = threadIdx.x;

    float lsum;
    if (bid < N_CORR_BLOCKS) {          // 0..11
        int layer = bid >> 2, bbase = (bid & 3) * 4;
        if (layer == 0)      lsum = corr_part<19,19,32,2>(o0, tgt, bbase, sbox, slin);
        else if (layer == 1) lsum = corr_part<38,38,16,1>(o1, tgt, bbase, sbox, slin);
        else                 lsum = corr_part<76,76,8,0>(o2, tgt, bbase, sbox, slin);
    } else {
        int mb = bid - N_CORR_BLOCKS;
        if (mb < 48) {
            lsum = main_part<19,19,2>(o0, tgt, mb / 3, mb % 3, &sbox[0][0], &sta4[0][0]);
        } else if (mb < 192) {
            int id = mb - 48;
            lsum = main_part<38,38,1>(o1, tgt, id / 9, id % 9, &sbox[0][0], &sta4[0][0]);
        } else {
            int id = mb - 192;
            lsum = main_part<76,76,0>(o2, tgt, id / 34, id % 34, &sbox[0][0], &sta4[0][0]);
        }
    }

    // block reduce -> one partial per block
    #pragma unroll
    for (int off = 32; off > 0; off >>= 1)
        lsum += __shfl_down(lsum, off);
    if ((tid & 63) == 0) wsums[tid >> 6] = lsum;
    __syncthreads();

    if (tid == 0) {
        float tot = wsums[0] + wsums[1] + wsums[2] + wsums[3];
        // device-scope atomic into spread slots: performed at coherent point, no L2 flush
        float old = atomicAdd(&g_slots[bid & 63], tot);
        asm volatile("" :: "v"(old) : "memory");   // force vmcnt ack before counter bump
        int cnt = atomicAdd(&g_count, 1);
        sflag = (cnt == N_BLOCKS - 1) ? 1 : 0;
    }
    __syncthreads();

    if (sflag && tid < 64) {            // last block, wave 0: deterministic 64-slot sum
        float v = __hip_atomic_load(&g_slots[tid], __ATOMIC_RELAXED, __HIP_MEMORY_SCOPE_AGENT);
        #pragma unroll
        for (int off = 32; off > 0; off >>= 1)
            v += __shfl_down(v, off);
        __hip_atomic_store(&g_slots[tid], 0.f, __ATOMIC_RELAXED, __HIP_MEMORY_SCOPE_AGENT);
        if (tid == 0) {
            *loss = v;
            __hip_atomic_store(&g_count, 0, __ATOMIC_RELAXED, __HIP_MEMORY_SCOPE_AGENT);
        }
    }
}

extern "C" void kernel_launch(void* const* d_in, const int* in_sizes, int n_in,
                              void* d_out, int out_size, void* d_ws, size_t ws_size,
                              hipStream_t stream) {
    const float* o0  = (const float*)d_in[0];
    const float* o1  = (const float*)d_in[1];
    const float* o2  = (const float*)d_in[2];
    const float* tgt = (const float*)d_in[3];
    float* loss = (float*)d_out;
    yolo_main<<<N_BLOCKS, 256, 0, stream>>>(o0, o1, o2, tgt, loss);
}

// Round 7
// 24.033 us; speedup vs baseline: 1.6769x; 1.1553x over previous
//
#include <hip/hip_runtime.h>
#include <math.h>

#define N_LABELS 50
#define NCLS 80
#define LOG2C 0.693147180559945f
#define N_CORR_BLOCKS 12
#define N_MAIN_BLOCKS 736
#define N_BLOCKS (N_MAIN_BLOCKS + N_CORR_BLOCKS)

__device__ __constant__ float d_anchors[9][2] = {
    {10.f,13.f},{16.f,30.f},{33.f,23.f},{30.f,61.f},{62.f,45.f},
    {59.f,119.f},{116.f,90.f},{156.f,198.f},{373.f,326.f}
};

// padded to 128B stride: each slot on its own cache line
__device__ float g_slots[64 * 32];   // zero-init at load; winner resets each call
__device__ int   g_scnt[64 * 32];
__device__ int   g_done;

__device__ __forceinline__ float softplus_f(float x) {      // == bce(x, 0)
    return fmaxf(x, 0.f) + __logf(1.f + __expf(-fabsf(x)));
}
__device__ __forceinline__ float bce_f(float x, float z) {
    return fmaxf(x, 0.f) - x * z + __logf(1.f + __expf(-fabsf(x)));
}
__device__ __forceinline__ float sigmoid_f(float x) {
    return __builtin_amdgcn_rcpf(1.f + __expf(-x));
}

// ---------------- main uniform pass: every cell, no divergence ----------------
template<int H, int W, int GROUP>
__device__ __forceinline__ float main_part(const float* __restrict__ out,
        const float* __restrict__ tgt, int b, int chunk,
        float4* sbox, float* sta)
{
    constexpr int HW = H * W;
    constexpr int NC = 3 * HW;
    constexpr int STRIDE = 608 / W;
    int tid = threadIdx.x;

    if (tid < N_LABELS) {
        const float* lp = tgt + ((size_t)b * N_LABELS + tid) * 5;
        float tx = lp[1] * (float)W, ty = lp[2] * (float)H;
        float tw = lp[3] * (float)W, th = lp[4] * (float)H;
        sbox[tid] = make_float4(tx - 0.5f*tw, ty - 0.5f*th, tx + 0.5f*tw, ty + 0.5f*th);
        sta[tid] = tw * th * (0.7f / 1.7f);
    }
    __syncthreads();

    const float* ob = out + (size_t)b * 255 * HW;
    int c0i = chunk * 512 + tid;
    float x0[2], x1[2], y0[2], y1[2], p07[2], c4v[2], whb[2], viol[2];
    bool valid[2];

    #pragma unroll
    for (int k = 0; k < 2; ++k) {
        int cell = c0i + k * 256;
        valid[k] = (cell < NC);
        int cc = valid[k] ? cell : 0;
        int a = cc / HW, rem = cc - a * HW;
        int hh = rem / W, ww = rem - hh * W;
        const float* base = ob + (size_t)a * 85 * HW + rem;
        float c0 = base[0];
        float c1 = base[HW];
        float c2 = base[2 * (size_t)HW];
        float c3 = base[3 * (size_t)HW];
        c4v[k] = base[4 * (size_t)HW];
        float aw = d_anchors[GROUP*3 + a][0] * (1.f / (float)STRIDE);
        float ah = d_anchors[GROUP*3 + a][1] * (1.f / (float)STRIDE);
        float pw = __expf(c2) * aw, ph = __expf(c3) * ah;
        float px = sigmoid_f(c0) + (float)ww;
        float py = sigmoid_f(c1) + (float)hh;
        x0[k] = px - 0.5f*pw; x1[k] = px + 0.5f*pw;
        y0[k] = py - 0.5f*ph; y1[k] = py + 0.5f*ph;
        p07[k] = pw * ph * (0.7f / 1.7f);
        whb[k] = 0.5f * (c2*c2 + c3*c3);      // unmasked wh (warm-up prior) term
        viol[k] = -1.f;
    }

    #pragma unroll 5
    for (int l = 0; l < N_LABELS; ++l) {
        float4 tb = sbox[l];
        float ta07 = sta[l];
        #pragma unroll
        for (int k = 0; k < 2; ++k) {
            float w_ = fminf(x1[k], tb.z) - fmaxf(x0[k], tb.x);
            float h_ = fminf(y1[k], tb.w) - fmaxf(y0[k], tb.y);
            float t  = ta07 + p07[k];
            // iou > 0.7  <=>  w>0 && h>0 && w*h > t   <=>  min3(w, h, w*h-t) > 0
            float m = fminf(fminf(w_, h_), __builtin_fmaf(w_, h_, -t));
            viol[k] = fmaxf(viol[k], m);
        }
    }

    float lsum = 0.f;
    #pragma unroll
    for (int k = 0; k < 2; ++k)
        if (valid[k])
            lsum += ((viol[k] > 0.f) ? LOG2C : softplus_f(c4v[k])) + 80.f * LOG2C + whb[k];
    return lsum;
}

// ---------------- correction pass: matched-label deltas (rare path) ----------------
template<int H, int W, int STRIDE, int GROUP>
__device__ __forceinline__ float corr_part(const float* __restrict__ out,
        const float* __restrict__ tgt, int bbase,
        float4 (*sbox)[N_LABELS], int* slin)
{
    constexpr int HW = H * W;
    int tid = threadIdx.x, wid = tid >> 6, lane = tid & 63;
    int b = bbase + wid;

    float tx=0, ty=0, tw=0, th=0, lw=0, lh=0, sc=0;
    int lin = -1, cls = 0;
    if (lane < N_LABELS) {
        const float* lp = tgt + ((size_t)b * N_LABELS + lane) * 5;
        cls = (int)lp[0];
        tx = lp[1] * (float)W; ty = lp[2] * (float)H;
        tw = lp[3] * (float)W; th = lp[4] * (float)H;
        float ta = tw * th;
        sbox[wid][lane] = make_float4(tx - 0.5f*tw, ty - 0.5f*th, tx + 0.5f*tw, ty + 0.5f*th);
        float best_iou = -1.f; int best = 0;
        #pragma unroll
        for (int kk = 0; kk < 9; ++kk) {
            float rw = d_anchors[kk][0] * (1.f / (float)STRIDE);
            float rh = d_anchors[kk][1] * (1.f / (float)STRIDE);
            float mx = fminf(tw, rw), my = fminf(th, rh);
            float inter = (mx > 0.f && my > 0.f) ? mx * my : 0.f;
            float iou = inter / (ta + rw * rh - inter);
            if (iou > best_iou) { best_iou = iou; best = kk; }
        }
        int bn = best - (best / 3) * 3;
        float aw = d_anchors[GROUP*3 + bn][0] * (1.f / (float)STRIDE);
        float ah = d_anchors[GROUP*3 + bn][1] * (1.f / (float)STRIDE);
        lw = __logf(tw / aw + 1e-16f);
        lh = __logf(th / ah + 1e-16f);
        sc = sqrtf(2.f - tw * th * (1.f / (float)HW));
        if (best / 3 == GROUP) {
            int ti = (int)tx, tj = (int)ty;
            lin = (bn * H + tj) * W + ti;
        }
    }
    slin[wid * 64 + lane] = lin;
    __syncthreads();

    bool active = (lin >= 0);
    if (active) {                       // last-write-wins on duplicate cells
        for (int l2 = lane + 1; l2 < N_LABELS; ++l2)
            if (slin[wid * 64 + l2] == lin) active = false;
    }

    float lsum = 0.f;
    if (active) {
        int a = lin / HW, rem = lin - a * HW;
        int hh = rem / W, ww = rem - hh * W;
        const float* base = out + ((size_t)b * 255 + (size_t)a * 85) * HW + rem;
        float c0 = base[0];
        float c1 = base[HW];
        float c2 = base[2 * (size_t)HW];
        float c3 = base[3 * (size_t)HW];
        float c4 = base[4 * (size_t)HW];
        float aw = d_anchors[GROUP*3 + a][0] * (1.f / (float)STRIDE);
        float ah = d_anchors[GROUP*3 + a][1] * (1.f / (float)STRIDE);
        float pw = __expf(c2) * aw, ph = __expf(c3) * ah;
        float px = sigmoid_f(c0) + (float)ww;
        float py = sigmoid_f(c1) + (float)hh;
        float X0 = px - 0.5f*pw, X1 = px + 0.5f*pw;
        float Y0 = py - 0.5f*ph, Y1 = py + 0.5f*ph;
        float p07 = pw * ph * (0.7f / 1.7f);
        bool ign = false;
        for (int l = 0; l < N_LABELS; ++l) {
            float4 tb = sbox[wid][l];
            float ta07 = (tb.z - tb.x) * (tb.w - tb.y) * (0.7f / 1.7f);
            float w_ = fminf(X1, tb.z) - fmaxf(X0, tb.x);
            float h_ = fminf(Y1, tb.w) - fmaxf(Y0, tb.y);
            ign = ign || ((fminf(w_, h_) > 0.f) && (w_ * h_ > ta07 + p07));
        }
        float baseobj = ign ? LOG2C : softplus_f(c4);   // what main_part added for obj
        lsum += bce_f(c4, 1.f) - baseobj;
        float s2 = sc * sc;
        float txf = tx - (float)(int)tx, tyf = ty - (float)(int)ty;
        lsum += (bce_f(c0, txf) + bce_f(c1, tyf)) * s2;
        float dw = c2 - lw, dh = c3 - lh;
        lsum += 0.5f * (dw*dw + dh*dh) * s2;
        float csum = 0.f;
        for (int c = 0; c < NCLS; ++c) {
            float lg = base[(size_t)(5 + c) * HW];
            csum += bce_f(lg, (c == cls) ? 1.f : 0.f);
        }
        lsum += csum - 80.f * LOG2C;
    }
    return lsum;
}

// Grid: corr: 12 (FIRST, overlapping their latency-bound tail) | then mains: 736.
// Single launch; hierarchical finish: slot float-add -> slot counter -> 64 slot-finishers
// bump g_done -> winner (g_done==63) reduces the 64 slots. Max same-address chain ~12+64.
__global__ __launch_bounds__(256) void yolo_main(
        const float* __restrict__ o0, const float* __restrict__ o1,
        const float* __restrict__ o2, const float* __restrict__ tgt,
        float* __restrict__ loss)
{
    __shared__ float4 sbox[4][N_LABELS];
    __shared__ float  sta4[4][N_LABELS];
    __shared__ int    slin[4 * 64];
    __shared__ float  wsums[4];
    __shared__ int    sflag;
    int bid = blockIdx.x, tid = threadIdx.x;

    float lsum;
    if (bid < N_CORR_BLOCKS) {          // 0..11
        int layer = bid >> 2, bbase = (bid & 3) * 4;
        if (layer == 0)      lsum = corr_part<19,19,32,2>(o0, tgt, bbase, sbox, slin);
        else if (layer == 1) lsum = corr_part<38,38,16,1>(o1, tgt, bbase, sbox, slin);
        else                 lsum = corr_part<76,76,8,0>(o2, tgt, bbase, sbox, slin);
    } else {
        int mb = bid - N_CORR_BLOCKS;
        if (mb < 48) {
            lsum = main_part<19,19,2>(o0, tgt, mb / 3, mb % 3, &sbox[0][0], &sta4[0][0]);
        } else if (mb < 192) {
            int id = mb - 48;
            lsum = main_part<38,38,1>(o1, tgt, id / 9, id % 9, &sbox[0][0], &sta4[0][0]);
        } else {
            int id = mb - 192;
            lsum = main_part<76,76,0>(o2, tgt, id / 34, id % 34, &sbox[0][0], &sta4[0][0]);
        }
    }

    // block reduce -> one partial per block
    #pragma unroll
    for (int off = 32; off > 0; off >>= 1)
        lsum += __shfl_down(lsum, off);
    if ((tid & 63) == 0) wsums[tid >> 6] = lsum;
    __syncthreads();

    if (tid == 0) {
        float tot = wsums[0] + wsums[1] + wsums[2] + wsums[3];
        int s = bid & 63;
        int expect = (s < 44) ? 12 : 11;            // 748 = 44*12 + 20*11
        float old = atomicAdd(&g_slots[s * 32], tot);
        asm volatile("" :: "v"(old) : "memory");    // order: slot add acked before counter
        int c = atomicAdd(&g_scnt[s * 32], 1);
        int flag = 0;
        if (c == expect - 1) {                      // slot finisher
            asm volatile("" :: "v"(c) : "memory");
            int d = atomicAdd(&g_done, 1);
            flag = (d == 63) ? 1 : 0;
        }
        sflag = flag;
    }
    __syncthreads();

    if (sflag && tid < 64) {            // winner block, wave 0: deterministic 64-slot sum
        float v = __hip_atomic_load(&g_slots[tid * 32], __ATOMIC_RELAXED, __HIP_MEMORY_SCOPE_AGENT);
        #pragma unroll
        for (int off = 32; off > 0; off >>= 1)
            v += __shfl_down(v, off);
        __hip_atomic_store(&g_slots[tid * 32], 0.f, __ATOMIC_RELAXED, __HIP_MEMORY_SCOPE_AGENT);
        __hip_atomic_store(&g_scnt[tid * 32], 0, __ATOMIC_RELAXED, __HIP_MEMORY_SCOPE_AGENT);
        if (tid == 0) {
            *loss = v;
            __hip_atomic_store(&g_done, 0, __ATOMIC_RELAXED, __HIP_MEMORY_SCOPE_AGENT);
        }
    }
}

extern "C" void kernel_launch(void* const* d_in, const int* in_sizes, int n_in,
                              void* d_out, int out_size, void* d_ws, size_t ws_size,
                              hipStream_t stream) {
    const float* o0  = (const float*)d_in[0];
    const float* o1  = (const float*)d_in[1];
    const float* o2  = (const float*)d_in[2];
    const float* tgt = (const float*)d_in[3];
    float* loss = (float*)d_out;
    yolo_main<<<N_BLOCKS, 256, 0, stream>>>(o0, o1, o2, tgt, loss);
}

// Round 8
// 23.762 us; speedup vs baseline: 1.6960x; 1.0114x over previous
//
#include <hip/hip_runtime.h>
#include <math.h>

#define N_LABELS 50
#define NCLS 80
#define LOG2C 0.693147180559945f
#define N_CORR_BLOCKS 12
#define N_MAIN_BLOCKS 736
#define N_BLOCKS (N_MAIN_BLOCKS + N_CORR_BLOCKS)

__device__ __constant__ float d_anchors[9][2] = {
    {10.f,13.f},{16.f,30.f},{33.f,23.f},{30.f,61.f},{62.f,45.f},
    {59.f,119.f},{116.f,90.f},{156.f,198.f},{373.f,326.f}
};

// padded to 128B stride: each slot on its own cache line
__device__ float g_slots[64 * 32];   // zero-init at load; winner resets each call
__device__ int   g_scnt[64 * 32];
__device__ int   g_done;

__device__ __forceinline__ float softplus_f(float x) {      // == bce(x, 0)
    return fmaxf(x, 0.f) + __logf(1.f + __expf(-fabsf(x)));
}
__device__ __forceinline__ float bce_f(float x, float z) {
    return fmaxf(x, 0.f) - x * z + __logf(1.f + __expf(-fabsf(x)));
}
__device__ __forceinline__ float sigmoid_f(float x) {
    return __builtin_amdgcn_rcpf(1.f + __expf(-x));
}

// ---------------- main uniform pass: every cell, no divergence ----------------
template<int H, int W, int GROUP>
__device__ __forceinline__ float main_part(const float* __restrict__ out,
        const float* __restrict__ tgt, int b, int chunk,
        float4* sbox, float* sta)
{
    constexpr int HW = H * W;
    constexpr int NC = 3 * HW;
    constexpr int STRIDE = 608 / W;
    int tid = threadIdx.x;

    // ---- issue ALL global loads first (channel loads + label loads), THEN barrier ----
    // channel loads are independent of LDS; issuing them before the staging barrier
    // overlaps their ~900cyc HBM latency with the label-staging latency.
    const float* ob = out + (size_t)b * 255 * HW;
    int c0i = chunk * 512 + tid;
    float c0v[2], c1v[2], c2v[2], c3v[2], c4v[2];
    int aidx[2], hhv[2], wwv[2];
    bool valid[2];
    #pragma unroll
    for (int k = 0; k < 2; ++k) {
        int cell = c0i + k * 256;
        valid[k] = (cell < NC);
        int cc = valid[k] ? cell : 0;
        int a = cc / HW, rem = cc - a * HW;
        aidx[k] = a; hhv[k] = rem / W; wwv[k] = rem - hhv[k] * W;
        const float* base = ob + (size_t)a * 85 * HW + rem;
        c0v[k] = base[0];
        c1v[k] = base[HW];
        c2v[k] = base[2 * (size_t)HW];
        c3v[k] = base[3 * (size_t)HW];
        c4v[k] = base[4 * (size_t)HW];
    }

    float ltx = 0.f, lty = 0.f, ltw = 0.f, lth = 0.f;
    if (tid < N_LABELS) {
        const float* lp = tgt + ((size_t)b * N_LABELS + tid) * 5;
        ltx = lp[1] * (float)W; lty = lp[2] * (float)H;
        ltw = lp[3] * (float)W; lth = lp[4] * (float)H;
        sbox[tid] = make_float4(ltx - 0.5f*ltw, lty - 0.5f*lth, ltx + 0.5f*ltw, lty + 0.5f*lth);
        sta[tid] = ltw * lth * (0.7f / 1.7f);
    }
    __syncthreads();

    float x0[2], x1[2], y0[2], y1[2], p07[2], whb[2], viol[2];
    #pragma unroll
    for (int k = 0; k < 2; ++k) {
        float aw = d_anchors[GROUP*3 + aidx[k]][0] * (1.f / (float)STRIDE);
        float ah = d_anchors[GROUP*3 + aidx[k]][1] * (1.f / (float)STRIDE);
        float pw = __expf(c2v[k]) * aw, ph = __expf(c3v[k]) * ah;
        float px = sigmoid_f(c0v[k]) + (float)wwv[k];
        float py = sigmoid_f(c1v[k]) + (float)hhv[k];
        x0[k] = px - 0.5f*pw; x1[k] = px + 0.5f*pw;
        y0[k] = py - 0.5f*ph; y1[k] = py + 0.5f*ph;
        p07[k] = pw * ph * (0.7f / 1.7f);
        whb[k] = 0.5f * (c2v[k]*c2v[k] + c3v[k]*c3v[k]);   // unmasked wh (warm-up prior) term
        viol[k] = -1.f;
    }

    #pragma unroll 5
    for (int l = 0; l < N_LABELS; ++l) {
        float4 tb = sbox[l];
        float ta07 = sta[l];
        #pragma unroll
        for (int k = 0; k < 2; ++k) {
            float w_ = fminf(x1[k], tb.z) - fmaxf(x0[k], tb.x);
            float h_ = fminf(y1[k], tb.w) - fmaxf(y0[k], tb.y);
            float t  = ta07 + p07[k];
            // iou > 0.7  <=>  w>0 && h>0 && w*h > t   <=>  min3(w, h, w*h-t) > 0
            float m = fminf(fminf(w_, h_), __builtin_fmaf(w_, h_, -t));
            viol[k] = fmaxf(viol[k], m);
        }
    }

    float lsum = 0.f;
    #pragma unroll
    for (int k = 0; k < 2; ++k)
        if (valid[k])
            lsum += ((viol[k] > 0.f) ? LOG2C : softplus_f(c4v[k])) + 80.f * LOG2C + whb[k];
    return lsum;
}

// ---------------- correction pass: matched-label deltas (rare path) ----------------
template<int H, int W, int STRIDE, int GROUP>
__device__ __forceinline__ float corr_part(const float* __restrict__ out,
        const float* __restrict__ tgt, int bbase,
        float4 (*sbox)[N_LABELS], int* slin)
{
    constexpr int HW = H * W;
    int tid = threadIdx.x, wid = tid >> 6, lane = tid & 63;
    int b = bbase + wid;

    float tx=0, ty=0, tw=0, th=0, lw=0, lh=0, sc=0;
    int lin = -1, cls = 0;
    if (lane < N_LABELS) {
        const float* lp = tgt + ((size_t)b * N_LABELS + lane) * 5;
        cls = (int)lp[0];
        tx = lp[1] * (float)W; ty = lp[2] * (float)H;
        tw = lp[3] * (float)W; th = lp[4] * (float)H;
        float ta = tw * th;
        sbox[wid][lane] = make_float4(tx - 0.5f*tw, ty - 0.5f*th, tx + 0.5f*tw, ty + 0.5f*th);
        float best_iou = -1.f; int best = 0;
        #pragma unroll
        for (int kk = 0; kk < 9; ++kk) {
            float rw = d_anchors[kk][0] * (1.f / (float)STRIDE);
            float rh = d_anchors[kk][1] * (1.f / (float)STRIDE);
            float mx = fminf(tw, rw), my = fminf(th, rh);
            float inter = (mx > 0.f && my > 0.f) ? mx * my : 0.f;
            float iou = inter / (ta + rw * rh - inter);
            if (iou > best_iou) { best_iou = iou; best = kk; }
        }
        int bn = best - (best / 3) * 3;
        float aw = d_anchors[GROUP*3 + bn][0] * (1.f / (float)STRIDE);
        float ah = d_anchors[GROUP*3 + bn][1] * (1.f / (float)STRIDE);
        lw = __logf(tw / aw + 1e-16f);
        lh = __logf(th / ah + 1e-16f);
        sc = sqrtf(2.f - tw * th * (1.f / (float)HW));
        if (best / 3 == GROUP) {
            int ti = (int)tx, tj = (int)ty;
            lin = (bn * H + tj) * W + ti;
        }
    }
    slin[wid * 64 + lane] = lin;
    __syncthreads();

    bool active = (lin >= 0);
    if (active) {                       // last-write-wins on duplicate cells
        for (int l2 = lane + 1; l2 < N_LABELS; ++l2)
            if (slin[wid * 64 + l2] == lin) active = false;
    }

    float lsum = 0.f;
    if (active) {
        int a = lin / HW, rem = lin - a * HW;
        int hh = rem / W, ww = rem - hh * W;
        const float* base = out + ((size_t)b * 255 + (size_t)a * 85) * HW + rem;
        float c0 = base[0];
        float c1 = base[HW];
        float c2 = base[2 * (size_t)HW];
        float c3 = base[3 * (size_t)HW];
        float c4 = base[4 * (size_t)HW];
        float aw = d_anchors[GROUP*3 + a][0] * (1.f / (float)STRIDE);
        float ah = d_anchors[GROUP*3 + a][1] * (1.f / (float)STRIDE);
        float pw = __expf(c2) * aw, ph = __expf(c3) * ah;
        float px = sigmoid_f(c0) + (float)ww;
        float py = sigmoid_f(c1) + (float)hh;
        float X0 = px - 0.5f*pw, X1 = px + 0.5f*pw;
        float Y0 = py - 0.5f*ph, Y1 = py + 0.5f*ph;
        float p07 = pw * ph * (0.7f / 1.7f);
        bool ign = false;
        for (int l = 0; l < N_LABELS; ++l) {
            float4 tb = sbox[wid][l];
            float ta07 = (tb.z - tb.x) * (tb.w - tb.y) * (0.7f / 1.7f);
            float w_ = fminf(X1, tb.z) - fmaxf(X0, tb.x);
            float h_ = fminf(Y1, tb.w) - fmaxf(Y0, tb.y);
            ign = ign || ((fminf(w_, h_) > 0.f) && (w_ * h_ > ta07 + p07));
        }
        float baseobj = ign ? LOG2C : softplus_f(c4);   // what main_part added for obj
        lsum += bce_f(c4, 1.f) - baseobj;
        float s2 = sc * sc;
        float txf = tx - (float)(int)tx, tyf = ty - (float)(int)ty;
        lsum += (bce_f(c0, txf) + bce_f(c1, tyf)) * s2;
        float dw = c2 - lw, dh = c3 - lh;
        lsum += 0.5f * (dw*dw + dh*dh) * s2;
        float csum = 0.f;
        for (int c = 0; c < NCLS; ++c) {
            float lg = base[(size_t)(5 + c) * HW];
            csum += bce_f(lg, (c == cls) ? 1.f : 0.f);
        }
        lsum += csum - 80.f * LOG2C;
    }
    return lsum;
}

// Grid: corr: 12 (FIRST, overlapping their latency-bound tail) | then mains: 736.
// Single launch; hierarchical finish: slot float-add -> slot counter -> 64 slot-finishers
// bump g_done -> winner (g_done==63) reduces the 64 slots. Max same-address chain ~12+64.
__global__ __launch_bounds__(256) void yolo_main(
        const float* __restrict__ o0, const float* __restrict__ o1,
        const float* __restrict__ o2, const float* __restrict__ tgt,
        float* __restrict__ loss)
{
    __shared__ float4 sbox[4][N_LABELS];
    __shared__ float  sta4[4][N_LABELS];
    __shared__ int    slin[4 * 64];
    __shared__ float  wsums[4];
    __shared__ int    sflag;
    int bid = blockIdx.x, tid = threadIdx.x;

    float lsum;
    if (bid < N_CORR_BLOCKS) {          // 0..11
        int layer = bid >> 2, bbase = (bid & 3) * 4;
        if (layer == 0)      lsum = corr_part<19,19,32,2>(o0, tgt, bbase, sbox, slin);
        else if (layer == 1) lsum = corr_part<38,38,16,1>(o1, tgt, bbase, sbox, slin);
        else                 lsum = corr_part<76,76,8,0>(o2, tgt, bbase, sbox, slin);
    } else {
        int mb = bid - N_CORR_BLOCKS;
        if (mb < 48) {
            lsum = main_part<19,19,2>(o0, tgt, mb / 3, mb % 3, &sbox[0][0], &sta4[0][0]);
        } else if (mb < 192) {
            int id = mb - 48;
            lsum = main_part<38,38,1>(o1, tgt, id / 9, id % 9, &sbox[0][0], &sta4[0][0]);
        } else {
            int id = mb - 192;
            lsum = main_part<76,76,0>(o2, tgt, id / 34, id % 34, &sbox[0][0], &sta4[0][0]);
        }
    }

    // block reduce -> one partial per block
    #pragma unroll
    for (int off = 32; off > 0; off >>= 1)
        lsum += __shfl_down(lsum, off);
    if ((tid & 63) == 0) wsums[tid >> 6] = lsum;
    __syncthreads();

    if (tid == 0) {
        float tot = wsums[0] + wsums[1] + wsums[2] + wsums[3];
        int s = bid & 63;
        int expect = (s < 44) ? 12 : 11;            // 748 = 44*12 + 20*11
        float old = atomicAdd(&g_slots[s * 32], tot);
        asm volatile("" :: "v"(old) : "memory");    // order: slot add acked before counter
        int c = atomicAdd(&g_scnt[s * 32], 1);
        int flag = 0;
        if (c == expect - 1) {                      // slot finisher
            asm volatile("" :: "v"(c) : "memory");
            int d = atomicAdd(&g_done, 1);
            flag = (d == 63) ? 1 : 0;
        }
        sflag = flag;
    }
    __syncthreads();

    if (sflag && tid < 64) {            // winner block, wave 0: deterministic 64-slot sum
        float v = __hip_atomic_load(&g_slots[tid * 32], __ATOMIC_RELAXED, __HIP_MEMORY_SCOPE_AGENT);
        #pragma unroll
        for (int off = 32; off > 0; off >>= 1)
            v += __shfl_down(v, off);
        __hip_atomic_store(&g_slots[tid * 32], 0.f, __ATOMIC_RELAXED, __HIP_MEMORY_SCOPE_AGENT);
        __hip_atomic_store(&g_scnt[tid * 32], 0, __ATOMIC_RELAXED, __HIP_MEMORY_SCOPE_AGENT);
        if (tid == 0) {
            *loss = v;
            __hip_atomic_store(&g_done, 0, __ATOMIC_RELAXED, __HIP_MEMORY_SCOPE_AGENT);
        }
    }
}

extern "C" void kernel_launch(void* const* d_in, const int* in_sizes, int n_in,
                              void* d_out, int out_size, void* d_ws, size_t ws_size,
                              hipStream_t stream) {
    const float* o0  = (const float*)d_in[0];
    const float* o1  = (const float*)d_in[1];
    const float* o2  = (const float*)d_in[2];
    const float* tgt = (const float*)d_in[3];
    float* loss = (float*)d_out;
    yolo_main<<<N_BLOCKS, 256, 0, stream>>>(o0, o1, o2, tgt, loss);
}